// Round 1
// baseline (280.883 us; speedup 1.0000x reference)
//
#include <hip/hip_runtime.h>

// out[b, d, l] = (x[l, b] < 20 ? embed_w[x[l, b], d] : 0) * sqrt(8)
// Shapes: x (L=2048, B=16) int32; embed_w (50257, 1024) fp32; out (16, 1024, 2048) fp32.
// Write-bound: 128 MiB of output. Each thread: 4 consecutive l (float4 store),
// loop over 32 d values. Grid (16, 2, 32) = 1024 blocks, 256 thr.

constexpr int D_MODEL = 1024;
constexpr int SEQ_LEN = 2048;
constexpr int BATCH   = 16;
constexpr int MAXTOK  = 20;
constexpr int LCHUNK  = 1024;   // l values per block = 256 threads * 4
constexpr int DPB     = 32;     // d values per block
__device__ constexpr float SCALE = 2.8284271247461903f; // sqrt(8)

__global__ __launch_bounds__(256) void embed_gather_kernel(
    const int* __restrict__ x,
    const float* __restrict__ w,
    float* __restrict__ out)
{
    const int b   = blockIdx.x;          // 0..15
    const int lc  = blockIdx.y;          // 0..1
    const int dc  = blockIdx.z;          // 0..31
    const int tid = threadIdx.x;         // 0..255

    const int l0 = lc * LCHUNK + tid * 4;    // first of 4 consecutive l's
    const int d0 = dc * DPB;

    // Load this thread's 4 tokens (x is (L, B), stride B between l's; tiny, L2-cached)
    const int tok0 = x[(l0 + 0) * BATCH + b];
    const int tok1 = x[(l0 + 1) * BATCH + b];
    const int tok2 = x[(l0 + 2) * BATCH + b];
    const int tok3 = x[(l0 + 3) * BATCH + b];

    const bool live0 = tok0 < MAXTOK;
    const bool live1 = tok1 < MAXTOK;
    const bool live2 = tok2 < MAXTOK;
    const bool live3 = tok3 < MAXTOK;
    const bool any   = live0 | live1 | live2 | live3;

    // out + b*D*L + d*L + l  ; lanes are consecutive in l -> coalesced float4
    float* outp = out + ((size_t)b * D_MODEL + d0) * SEQ_LEN + l0;

    if (!any) {
        // Fast path: pure zero-fill of a DPB x 4 tile (the ~99.96% case)
        const float4 z = make_float4(0.f, 0.f, 0.f, 0.f);
        #pragma unroll
        for (int i = 0; i < DPB; ++i) {
            *reinterpret_cast<float4*>(outp) = z;
            outp += SEQ_LEN;
        }
    } else {
        const float* w0 = w + (size_t)tok0 * D_MODEL + d0;
        const float* w1 = w + (size_t)tok1 * D_MODEL + d0;
        const float* w2 = w + (size_t)tok2 * D_MODEL + d0;
        const float* w3 = w + (size_t)tok3 * D_MODEL + d0;
        #pragma unroll 4
        for (int i = 0; i < DPB; ++i) {
            float4 v;
            v.x = live0 ? w0[i] * SCALE : 0.f;
            v.y = live1 ? w1[i] * SCALE : 0.f;
            v.z = live2 ? w2[i] * SCALE : 0.f;
            v.w = live3 ? w3[i] * SCALE : 0.f;
            *reinterpret_cast<float4*>(outp) = v;
            outp += SEQ_LEN;
        }
    }
}

extern "C" void kernel_launch(void* const* d_in, const int* in_sizes, int n_in,
                              void* d_out, int out_size, void* d_ws, size_t ws_size,
                              hipStream_t stream) {
    const int*   x = (const int*)d_in[0];     // (2048, 16) token ids
    const float* w = (const float*)d_in[1];   // (50257, 1024)
    float*     out = (float*)d_out;           // (16, 1024, 2048)

    dim3 grid(BATCH, SEQ_LEN / LCHUNK, D_MODEL / DPB);  // (16, 2, 32)
    dim3 block(256);
    embed_gather_kernel<<<grid, block, 0, stream>>>(x, w, out);
}

// Round 2
// 278.767 us; speedup vs baseline: 1.0076x; 1.0076x over previous
//
#include <hip/hip_runtime.h>

// out[b, d, l] = (x[l, b] < 20 ? embed_w[x[l, b], d] : 0) * sqrt(8)
// Shapes: x (L=2048, B=16) int32; embed_w (50257, 1024) fp32; out (16, 1024, 2048) fp32.
// Pure write-bound: 128 MiB output, ~99.96% zeros (tokens uniform in [0,50257), live < 20).
// R2 structure: 4096 blocks (16/CU). Block = (b, l-chunk of 256, d-chunk of 32).
// All 4 waves share the same 256 tokens (L1 dedups the uncoalesced x reads);
// each wave owns 8 d-rows; each lane stores 8 float4 (128 B) = fully coalesced
// 1 KB/wave/row stores.

constexpr int D_MODEL = 1024;
constexpr int SEQ_LEN = 2048;
constexpr int BATCH   = 16;
constexpr int MAXTOK  = 20;
constexpr int LPB     = 256;   // l per block = 64 lanes * 4
constexpr int DPB     = 32;    // d per block = 4 waves * 8 rows
__device__ constexpr float SCALE = 2.8284271247461903f; // sqrt(8)

__global__ __launch_bounds__(256) void embed_gather_kernel(
    const int* __restrict__ x,
    const float* __restrict__ w,
    float* __restrict__ out)
{
    const int b    = blockIdx.x;          // 0..15
    const int lc   = blockIdx.y;          // 0..7
    const int dc   = blockIdx.z;          // 0..31
    const int lane = threadIdx.x & 63;
    const int wv   = threadIdx.x >> 6;    // 0..3

    const int l0 = lc * LPB + lane * 4;        // 4 consecutive l's per lane
    const int d0 = dc * DPB + wv * 8;          // 8 d-rows per wave

    // 4 token loads, stride 64 B (uncoalesced but L1/L2-resident; shared by all
    // 4 waves of the block -> L1 dedup).
    const int tok0 = x[(l0 + 0) * BATCH + b];
    const int tok1 = x[(l0 + 1) * BATCH + b];
    const int tok2 = x[(l0 + 2) * BATCH + b];
    const int tok3 = x[(l0 + 3) * BATCH + b];

    const bool live0 = tok0 < MAXTOK;
    const bool live1 = tok1 < MAXTOK;
    const bool live2 = tok2 < MAXTOK;
    const bool live3 = tok3 < MAXTOK;
    const bool any   = live0 | live1 | live2 | live3;

    float* outp = out + ((size_t)b * D_MODEL + d0) * SEQ_LEN + l0;

    if (!any) {
        // ~99.96% path: zero-fill an 8x4 tile, coalesced float4 stores.
        const float4 z = make_float4(0.f, 0.f, 0.f, 0.f);
        #pragma unroll
        for (int i = 0; i < 8; ++i) {
            *reinterpret_cast<float4*>(outp) = z;
            outp += SEQ_LEN;
        }
    } else {
        const float* w0 = w + (size_t)tok0 * D_MODEL + d0;
        const float* w1 = w + (size_t)tok1 * D_MODEL + d0;
        const float* w2 = w + (size_t)tok2 * D_MODEL + d0;
        const float* w3 = w + (size_t)tok3 * D_MODEL + d0;
        #pragma unroll
        for (int i = 0; i < 8; ++i) {
            float4 v;
            v.x = live0 ? w0[i] * SCALE : 0.f;
            v.y = live1 ? w1[i] * SCALE : 0.f;
            v.z = live2 ? w2[i] * SCALE : 0.f;
            v.w = live3 ? w3[i] * SCALE : 0.f;
            *reinterpret_cast<float4*>(outp) = v;
            outp += SEQ_LEN;
        }
    }
}

extern "C" void kernel_launch(void* const* d_in, const int* in_sizes, int n_in,
                              void* d_out, int out_size, void* d_ws, size_t ws_size,
                              hipStream_t stream) {
    const int*   x = (const int*)d_in[0];     // (2048, 16) token ids
    const float* w = (const float*)d_in[1];   // (50257, 1024)
    float*     out = (float*)d_out;           // (16, 1024, 2048)

    dim3 grid(BATCH, SEQ_LEN / LPB, D_MODEL / DPB);  // (16, 8, 32) = 4096 blocks
    dim3 block(256);
    embed_gather_kernel<<<grid, block, 0, stream>>>(x, w, out);
}